// Round 5
// baseline (188.721 us; speedup 1.0000x reference)
//
#include <hip/hip_runtime.h>
#include <hip/hip_bf16.h>

#define NROWS 400000
#define MSEL  100000
#define FDIM  128
#define D0 256
#define D1 256
#define D2 128

typedef __attribute__((ext_vector_type(8))) short short8;
typedef __attribute__((ext_vector_type(4))) float f32x4;
typedef __attribute__((ext_vector_type(4))) unsigned short ushort4v;
typedef __attribute__((ext_vector_type(2))) unsigned int uint2v;

__device__ __forceinline__ unsigned short f2bf(float f) {
    unsigned int u = __float_as_uint(f);
    unsigned int r = (u + 0x7fffu + ((u >> 16) & 1u)) >> 16;
    return (unsigned short)r;
}

// packed f32x2 -> bf16x2 via v_cvt_pk_bf16_f32
__device__ __forceinline__ unsigned int pk2bf(float a, float b) {
    __hip_bfloat162 h = __float22bfloat162_rn(make_float2(a, b));
    return *(unsigned int*)&h;
}

__device__ __forceinline__ float bf2f(unsigned short u) {
    return __uint_as_float(((unsigned int)u) << 16);
}

__device__ __forceinline__ float elu(float v) {
    return v > 0.f ? v : (__expf(v) - 1.f);
}

// ---------------------------------------------------------------------------
// Repack f32 weights into bf16 B-fragment order for mfma_f32_16x16x32_bf16.
// Tile (kt,nt) is 32x16; lane l holds B[kt*32+(l>>4)*8+j][nt*16+(l&15)], 8 bf16
// contiguous per lane.  ws: W0p [0,32768) shorts, W1p [32768,98304),
// W2p [98304,131072).
// ---------------------------------------------------------------------------
__global__ void pack_weights(const float* __restrict__ W0,
                             const float* __restrict__ W1,
                             const float* __restrict__ W2,
                             short* __restrict__ out) {
    int e = blockIdx.x * 256 + threadIdx.x;
    if (e >= 131072) return;
    const float* W; int N; int base; int le;
    if (e < 32768)       { W = W0; N = 256; base = 0;     le = e; }
    else if (e < 98304)  { W = W1; N = 256; base = 32768; le = e - 32768; }
    else                 { W = W2; N = 128; base = 98304; le = e - 98304; }
    int t    = le >> 9;
    int r    = le & 511;
    int lane = r >> 3;
    int j    = r & 7;
    int ntiles = N >> 4;
    int kt = t / ntiles, nt = t % ntiles;
    int k = kt * 32 + (lane >> 4) * 8 + j;
    int n = nt * 16 + (lane & 15);
    out[base + le] = (short)f2bf(W[k * N + n]);
}

__global__ void copy_x(const float4* __restrict__ x, float4* __restrict__ out, int n4) {
    int i = blockIdx.x * blockDim.x + threadIdx.x;
    int stride = gridDim.x * blockDim.x;
    for (; i < n4; i += stride) out[i] = x[i];
}

// ---------------------------------------------------------------------------
// Inverted index of sel: head[r] -> last j with sel[j]==r, next[j] -> chain.
// Chain LENGTH (and hence the single-contributor property next[j]==-1 &&
// head[sel[j]]==j) is deterministic even though insertion order is not.
// ---------------------------------------------------------------------------
__global__ void init_head(int* __restrict__ head) {
    int i = blockIdx.x * 256 + threadIdx.x;
    int s = gridDim.x * 256;
    for (; i < NROWS; i += s) head[i] = -1;
}

__global__ void build_links(const int* __restrict__ sel,
                            int* __restrict__ head, int* __restrict__ next) {
    int j = blockIdx.x * 256 + threadIdx.x;
    if (j < MSEL) {
        int r = sel[j];
        next[j] = atomicExch(head + r, j);
    }
}

// ---------------------------------------------------------------------------
// Gather -> 3-layer ELU MLP (bf16 MFMA).  Block = 256 thr = 4 waves, 32 rows.
// Each wave computes ALL 32 rows x a 64-col slice (32-col for layer 2);
// B-fragments register-resident per layer.  LDS 40KB -> 4 blocks/CU.
// XOR swizzle shortIdx ^= (row&7)<<3 breaks ds_read_b128 bank conflicts.
// Epilogue 2: single-contributor rows -> write out[r] = bf16(x[r]) + up
// directly (f32); multi rows -> write up[j] (bf16) for the merge kernel.
// ---------------------------------------------------------------------------
template <bool SPLIT>
__global__ __launch_bounds__(256) void mlp_compute(
    const float* __restrict__ x, const int* __restrict__ sel,
    const short* __restrict__ wp,
    const float* __restrict__ b0v, const float* __restrict__ b1v,
    const float* __restrict__ b2v,
    const int* __restrict__ head, const int* __restrict__ next,
    unsigned short* __restrict__ upOut, float* __restrict__ out) {
    __shared__ __align__(16) short lds[20480];

    const int tid  = threadIdx.x;
    const int lane = tid & 63;
    const int w    = tid >> 6;
    const int rowBase = blockIdx.x * 32;
    const int lm = lane & 15;
    const int kq = lane >> 4;
    const int sxz = (lm & 7) << 3;

    const short* W0p = wp;
    const short* W1p = wp + 32768;
    const short* W2p = wp + 98304;

    // prefetch layer-0 B fragments (hide under gather)
    short8 B0[4][4];
    #pragma unroll
    for (int kt = 0; kt < 4; kt++)
        #pragma unroll
        for (int ntl = 0; ntl < 4; ntl++)
            B0[kt][ntl] = *(const short8*)(W0p + ((kt * 16 + (w * 4 + ntl)) * 512 + lane * 8));

    // gather: 32 rows x 128 f32 -> bf16 into LDS (paired hw cvt, b64 writes)
    const float4* xv = (const float4*)x;
    #pragma unroll
    for (int it = 0; it < 4; it++) {
        int i = it * 256 + tid;
        int row = i >> 5, seg = i & 31;
        float4 v = xv[(size_t)sel[rowBase + row] * 32 + seg];
        uint2v p = { pk2bf(v.x, v.y), pk2bf(v.z, v.w) };
        *(uint2v*)(&lds[(row * 128 + seg * 4) ^ ((row & 7) << 3)]) = p;
    }
    __syncthreads();

    const f32x4 zero4 = {0.f, 0.f, 0.f, 0.f};

    // ===== layer 0: (32x128) @ W0(128x256) =====
    {
        f32x4 acc[2][4];
        #pragma unroll
        for (int i = 0; i < 2; i++)
            #pragma unroll
            for (int j = 0; j < 4; j++) acc[i][j] = zero4;
        #pragma unroll
        for (int rt = 0; rt < 2; rt++) {
            short8 a[4];
            int rowA = rt * 16 + lm;
            #pragma unroll
            for (int kt = 0; kt < 4; kt++)
                a[kt] = *(const short8*)(&lds[(rowA * 128 + kt * 32 + kq * 8) ^ sxz]);
            #pragma unroll
            for (int ntl = 0; ntl < 4; ntl++)
                #pragma unroll
                for (int kt = 0; kt < 4; kt++)
                    acc[rt][ntl] = __builtin_amdgcn_mfma_f32_16x16x32_bf16(a[kt], B0[kt][ntl], acc[rt][ntl], 0, 0, 0);
        }
        #pragma unroll
        for (int ntl = 0; ntl < 4; ntl++) {
            int col = (w * 4 + ntl) * 16 + lm;
            float bias = b0v[col];
            #pragma unroll
            for (int rt = 0; rt < 2; rt++) {
                float v0 = elu(acc[rt][ntl][0] + bias);
                float v1 = elu(acc[rt][ntl][1] + bias);
                float v2 = elu(acc[rt][ntl][2] + bias);
                float v3 = elu(acc[rt][ntl][3] + bias);
                unsigned int u01 = pk2bf(v0, v1), u23 = pk2bf(v2, v3);
                int row = rt * 16 + kq * 4;
                lds[4096 + (((row+0) * 256 + col) ^ (((row+0) & 7) << 3))] = (short)(u01 & 0xffff);
                lds[4096 + (((row+1) * 256 + col) ^ (((row+1) & 7) << 3))] = (short)(u01 >> 16);
                lds[4096 + (((row+2) * 256 + col) ^ (((row+2) & 7) << 3))] = (short)(u23 & 0xffff);
                lds[4096 + (((row+3) * 256 + col) ^ (((row+3) & 7) << 3))] = (short)(u23 >> 16);
            }
        }
    }
    __syncthreads();

    // ===== layer 1: (32x256) @ W1(256x256), 2 col-passes =====
    #pragma unroll
    for (int pass = 0; pass < 2; pass++) {
        short8 B1[8][2];
        #pragma unroll
        for (int kt = 0; kt < 8; kt++)
            #pragma unroll
            for (int p = 0; p < 2; p++)
                B1[kt][p] = *(const short8*)(W1p + ((kt * 16 + (w * 4 + pass * 2 + p)) * 512 + lane * 8));
        f32x4 acc[2][2];
        #pragma unroll
        for (int i = 0; i < 2; i++)
            #pragma unroll
            for (int j = 0; j < 2; j++) acc[i][j] = zero4;
        #pragma unroll
        for (int rt = 0; rt < 2; rt++) {
            short8 a[8];
            int rowA = rt * 16 + lm;
            #pragma unroll
            for (int kt = 0; kt < 8; kt++)
                a[kt] = *(const short8*)(&lds[4096 + ((rowA * 256 + kt * 32 + kq * 8) ^ sxz)]);
            #pragma unroll
            for (int p = 0; p < 2; p++)
                #pragma unroll
                for (int kt = 0; kt < 8; kt++)
                    acc[rt][p] = __builtin_amdgcn_mfma_f32_16x16x32_bf16(a[kt], B1[kt][p], acc[rt][p], 0, 0, 0);
        }
        #pragma unroll
        for (int p = 0; p < 2; p++) {
            int col = (w * 4 + pass * 2 + p) * 16 + lm;
            float bias = b1v[col];
            #pragma unroll
            for (int rt = 0; rt < 2; rt++) {
                float v0 = elu(acc[rt][p][0] + bias);
                float v1 = elu(acc[rt][p][1] + bias);
                float v2 = elu(acc[rt][p][2] + bias);
                float v3 = elu(acc[rt][p][3] + bias);
                unsigned int u01 = pk2bf(v0, v1), u23 = pk2bf(v2, v3);
                int row = rt * 16 + kq * 4;
                lds[12288 + (((row+0) * 256 + col) ^ (((row+0) & 7) << 3))] = (short)(u01 & 0xffff);
                lds[12288 + (((row+1) * 256 + col) ^ (((row+1) & 7) << 3))] = (short)(u01 >> 16);
                lds[12288 + (((row+2) * 256 + col) ^ (((row+2) & 7) << 3))] = (short)(u23 & 0xffff);
                lds[12288 + (((row+3) * 256 + col) ^ (((row+3) & 7) << 3))] = (short)(u23 >> 16);
            }
        }
    }
    __syncthreads();

    // ===== layer 2: (32x256) @ W2(256x128) =====
    {
        short8 B2[8][2];
        #pragma unroll
        for (int kt = 0; kt < 8; kt++)
            #pragma unroll
            for (int ntl = 0; ntl < 2; ntl++)
                B2[kt][ntl] = *(const short8*)(W2p + ((kt * 8 + (w * 2 + ntl)) * 512 + lane * 8));

        // row bookkeeping: selected index j, target row rr, single-contributor?
        int jj[2][4]; int rr[2][4]; bool sg[2][4];
        #pragma unroll
        for (int rt = 0; rt < 2; rt++)
            #pragma unroll
            for (int r = 0; r < 4; r++) {
                int j = rowBase + rt * 16 + kq * 4 + r;
                jj[rt][r] = j;
                int t = sel[j];
                rr[rt][r] = t;
                if (SPLIT) sg[rt][r] = (next[j] < 0) && (head[t] == j);
                else       sg[rt][r] = false;
            }

        f32x4 acc[2][2];
        #pragma unroll
        for (int i = 0; i < 2; i++)
            #pragma unroll
            for (int j = 0; j < 2; j++) acc[i][j] = zero4;
        #pragma unroll
        for (int rt = 0; rt < 2; rt++) {
            short8 a[8];
            int rowA = rt * 16 + lm;
            #pragma unroll
            for (int kt = 0; kt < 8; kt++)
                a[kt] = *(const short8*)(&lds[12288 + ((rowA * 256 + kt * 32 + kq * 8) ^ sxz)]);
            #pragma unroll
            for (int ntl = 0; ntl < 2; ntl++)
                #pragma unroll
                for (int kt = 0; kt < 8; kt++)
                    acc[rt][ntl] = __builtin_amdgcn_mfma_f32_16x16x32_bf16(a[kt], B2[kt][ntl], acc[rt][ntl], 0, 0, 0);
        }
        #pragma unroll
        for (int ntl = 0; ntl < 2; ntl++) {
            int col = (w * 2 + ntl) * 16 + lm;
            float bias = b2v[col];
            #pragma unroll
            for (int rt = 0; rt < 2; rt++)
                #pragma unroll
                for (int r = 0; r < 4; r++) {
                    int lrow = rt * 16 + kq * 4 + r;
                    float v = elu(acc[rt][ntl][r] + bias);
                    if (SPLIT) {
                        if (sg[rt][r]) {
                            // single contributor: finalize out row here
                            float xb = bf2f((unsigned short)lds[(lrow * 128 + col) ^ ((lrow & 7) << 3)]);
                            out[(size_t)rr[rt][r] * 128 + col] = xb + v;
                        } else {
                            upOut[(size_t)jj[rt][r] * 128 + col] = f2bf(v);
                        }
                    } else {
                        atomicAdd(out + (size_t)rr[rt][r] * 128 + col, v);
                    }
                }
        }
    }
}

// ---------------------------------------------------------------------------
// merge: wave per row.  head==-1 -> copy; chain len 1 -> skip (compute wrote
// it); chain len>=2 -> out[r] = x[r] + sum up[j].  All branches wave-uniform.
// ---------------------------------------------------------------------------
__global__ __launch_bounds__(256) void merge_out(
    const float2* __restrict__ x2, const unsigned int* __restrict__ up32,
    const int* __restrict__ head, const int* __restrict__ next,
    float2* __restrict__ out2) {
    int wid  = blockIdx.x * 4 + (threadIdx.x >> 6);
    int lane = threadIdx.x & 63;
    int wstride = gridDim.x * 4;
    for (int row = wid; row < NROWS; row += wstride) {
        int j = head[row];
        if (j < 0) {
            out2[(size_t)row * 64 + lane] = x2[(size_t)row * 64 + lane];
        } else {
            int nx = next[j];
            if (nx < 0) continue;             // single: already written
            float2 v = x2[(size_t)row * 64 + lane];
            while (j >= 0) {
                unsigned int u = up32[(size_t)j * 64 + lane];
                v.x += __uint_as_float(u << 16);
                v.y += __uint_as_float(u & 0xffff0000u);
                j = next[j];
            }
            out2[(size_t)row * 64 + lane] = v;
        }
    }
}

extern "C" void kernel_launch(void* const* d_in, const int* in_sizes, int n_in,
                              void* d_out, int out_size, void* d_ws, size_t ws_size,
                              hipStream_t stream) {
    const float* x   = (const float*)d_in[0];
    const int*   sel = (const int*)d_in[1];
    const float* W0  = (const float*)d_in[2];
    const float* b0  = (const float*)d_in[3];
    const float* W1  = (const float*)d_in[4];
    const float* b1  = (const float*)d_in[5];
    const float* W2  = (const float*)d_in[6];
    const float* b2  = (const float*)d_in[7];
    float* out = (float*)d_out;

    char* wsb = (char*)d_ws;
    short* wp          = (short*)wsb;                                  // 262144 B
    unsigned short* up = (unsigned short*)(wsb + 262144);              // 25.6 MB
    int* head          = (int*)(wsb + 262144 + (size_t)MSEL * 256);    // 1.6 MB
    int* nxt           = head + NROWS;                                 // 0.4 MB
    const size_t need  = 262144 + (size_t)MSEL * 256 + (size_t)NROWS * 4 + (size_t)MSEL * 4;

    pack_weights<<<512, 256, 0, stream>>>(W0, W1, W2, wp);
    if (ws_size >= need) {
        init_head<<<1024, 256, 0, stream>>>(head);
        build_links<<<(MSEL + 255) / 256, 256, 0, stream>>>(sel, head, nxt);
        mlp_compute<true><<<MSEL / 32, 256, 0, stream>>>(x, sel, wp, b0, b1, b2, head, nxt, up, out);
        merge_out<<<4096, 256, 0, stream>>>((const float2*)x, (const unsigned int*)up,
                                            head, nxt, (float2*)out);
    } else {
        copy_x<<<4096, 256, 0, stream>>>((const float4*)x, (float4*)out, NROWS * FDIM / 4);
        mlp_compute<false><<<MSEL / 32, 256, 0, stream>>>(x, sel, wp, b0, b1, b2, head, nxt, up, out);
    }
}